// Round 10
// baseline (123.016 us; speedup 1.0000x reference)
//
#include <hip/hip_runtime.h>
#include <hip/hip_bf16.h>

typedef __attribute__((ext_vector_type(8))) short short8;
typedef __attribute__((ext_vector_type(4))) float f32x4;

#define DDIM 256
#define NROWS 131072
#define RG 256
#define GBLK (RG * 2)         // 512 blocks: bid = rg*2 + half
#define RPG (NROWS / RG)      // 512 rows per block
#define TROWS 128             // X tile: 128 rows x 32 cols fp32 = 16 KB
#define NTILE 32              // 4 row-chunks x 8 k-tiles
#define RING 5                // ring slots (reuse distance = 2 barriers)
#define AHEAD 3               // tiles issued ahead (48 KB/CU in flight)
#define XTILE 16384

static __device__ __forceinline__ unsigned short f2bf(float f){
  unsigned b = __builtin_bit_cast(unsigned, f);
  b += 0x7FFFu + ((b >> 16) & 1u);          // RNE round to bf16
  return (unsigned short)(b >> 16);
}

static __device__ __forceinline__ float wave_sum_bcast(float x){
  int v = __builtin_bit_cast(int, x);
#define DPP_ADD(ctrl)                                                          \
  v = __builtin_bit_cast(int,                                                  \
        __builtin_bit_cast(float, v) +                                         \
        __builtin_bit_cast(float,                                              \
          __builtin_amdgcn_update_dpp(0, v, (ctrl), 0xF, 0xF, true)))
  DPP_ADD(0x111); DPP_ADD(0x112); DPP_ADD(0x114); DPP_ADD(0x118);
  DPP_ADD(0x142); DPP_ADD(0x143);
#undef DPP_ADD
  return __builtin_bit_cast(float, __builtin_amdgcn_readlane(v, 63));
}

// ---------------------------------------------------------------------------
// Kernel A (unchanged from r9, verified): Q columns via 256 Householder steps.
// ---------------------------------------------------------------------------
__global__ __launch_bounds__(256) void compute_q(const float* __restrict__ U,
                                                 unsigned short* __restrict__ Qt){
  const int lane = threadIdx.x & 63;
  const int wv   = threadIdx.x >> 6;
  const int pair = blockIdx.x * 4 + wv;
  const int j0 = pair * 2, j1 = j0 + 1;

  float u0[4], u1[4], r0[4], r1[4], r2[4], r3[4];
#pragma unroll
  for (int e = 0; e < 4; ++e){
    const int i = e * 64 + lane;
    u0[e] = (i == j0) ? 1.f : 0.f;
    u1[e] = (i == j1) ? 1.f : 0.f;
    r0[e] = U[0 * 256 + i];
    r1[e] = U[1 * 256 + i];
    r2[e] = U[2 * 256 + i];
    r3[e] = U[3 * 256 + i];
  }

#define QSTEP(R, KN)                                                           \
  do {                                                                         \
    const float p0_ = (u0[0]*R[0] + u0[1]*R[1]) + (u0[2]*R[2] + u0[3]*R[3]);   \
    const float p1_ = (u1[0]*R[0] + u1[1]*R[1]) + (u1[2]*R[2] + u1[3]*R[3]);   \
    const float pv_ = (R[0]*R[0] + R[1]*R[1]) + (R[2]*R[2] + R[3]*R[3]);       \
    const float d0_ = wave_sum_bcast(p0_);                                     \
    const float d1_ = wave_sum_bcast(p1_);                                     \
    const float dv_ = wave_sum_bcast(pv_);                                     \
    const float inv_ = 2.0f * __builtin_amdgcn_rcpf(dv_);                      \
    const float c0_ = d0_ * inv_, c1_ = d1_ * inv_;                            \
    _Pragma("unroll")                                                          \
    for (int e = 0; e < 4; ++e){                                               \
      u0[e] = fmaf(-c0_, R[e], u0[e]);                                         \
      u1[e] = fmaf(-c1_, R[e], u1[e]);                                         \
      R[e] = U[(size_t)(KN) * 256 + e * 64 + lane];                            \
    }                                                                          \
  } while (0)

  for (int k = 0; k < 256; k += 4){
    const int k4 = (k+4) & 255, k5 = (k+5) & 255, k6 = (k+6) & 255, k7 = (k+7) & 255;
    QSTEP(r0, k4); QSTEP(r1, k5); QSTEP(r2, k6); QSTEP(r3, k7);
  }
#undef QSTEP

#pragma unroll
  for (int e = 0; e < 4; ++e){
    const int i = e * 64 + lane;
    Qt[(size_t)j0 * 256 + i] = f2bf(u0[e]);
    Qt[(size_t)j1 * 256 + i] = f2bf(u1[e]);
  }
}

// ---------------------------------------------------------------------------
// Kernel B: Y = X * Q, counted-vmcnt global_load_lds ring (T3+T4).
// 512 blocks x 512 thr; block = 512 rows x 128-col half (bid pairing keeps
// the duplicate X read L3-hot, verified r7).  LDS: Qt-half 64KB + 5x16KB X
// ring = 144KB (1 block/CU).  Phase t: STAGE(t+3) -> s_waitcnt vmcnt(W) ->
// s_barrier -> consume(t).  3 tiles (48KB/CU) stay in flight continuously;
// no vmcnt(0) drain in the loop.  Stores are nontemporal (Y won't evict X
// from L3 across timed replays); they count in vmcnt -> W += 32 on the
// AHEAD phases after each store burst.
// Swizzles (both-sides-or-neither, rule 21; source pre-swizzled):
//   Qt: phys 16B-slot = s ^ ((nl&15)<<1); read byte = kb ^ ((nl&15)<<5)  [r5/r7: 0 conflicts]
//   X:  phys 16B-slot = s ^ (row&7);      read byte = off ^ ((row&7)<<4) [2-way = free]
// mfma_f32_16x16x32_bf16 layouts (m89/m97):
//   A: lane holds A[l&15][kk*32+8*(l>>4)+j]   B: same, n=l&15
//   D: D[(l>>4)*4+r][l&15]
// ---------------------------------------------------------------------------
static __device__ __forceinline__ void gl16(const void* g, void* l){
  __builtin_amdgcn_global_load_lds(
      (const __attribute__((address_space(1))) unsigned int*)g,
      (__attribute__((address_space(3))) unsigned int*)l, 16, 0, 0);
}

__host__ __device__ constexpr int wcnt(int t){
  const int rem = (NTILE - 1) - t;
  const int inflight = rem < AHEAD ? rem : AHEAD;
  int w = 2 * inflight;
  if (t >= 8 && (t & 7) <= (AHEAD - 1)) w += 32;   // stores from phase t-(t&7)-1 are newer than tile t's loads
  return w;
}

__global__ __launch_bounds__(512) void gemm_xq(const float* __restrict__ X,
                                               const unsigned short* __restrict__ Qt,
                                               float* __restrict__ Y){
  __shared__ __attribute__((aligned(16))) char qb[65536];       // Qt half
  __shared__ __attribute__((aligned(16))) char ring[RING * XTILE];

  const int tid  = threadIdx.x;
  const int lane = tid & 63;
  const int wv   = tid >> 6;                  // 0..7
  const int lg   = lane >> 4;                 // 0..3
  const int lm   = lane & 15;
  const int half = blockIdx.x & 1;
  const size_t rowbase = (size_t)(blockIdx.x >> 1) * RPG;

  // --- Qt half -> LDS via global_load_lds (source pre-swizzled) ---
  {
    const char* qsrc = (const char*)Qt + ((size_t)half * 128) * 512;
#pragma unroll
    for (int it = 0; it < 8; ++it){
      const int c  = tid + it * 512;          // 0..4095 16B chunks
      const int nl = c >> 5;
      const int sl = (c & 31) ^ ((nl & 15) << 1);
      gl16(qsrc + (size_t)nl * 512 + sl * 16, qb + (it * 512 + wv * 64) * 16);
    }
  }

#define STAGE(u) do{                                                           \
    char* sb_ = ring + ((u) % RING) * XTILE;                                   \
    const char* gb_ = (const char*)X +                                         \
        (rowbase + (size_t)((u) >> 3) * TROWS) * 1024 + ((u) & 7) * 128;       \
    { const int c_ = tid;       const int r_ = c_ >> 3;                        \
      const int sl_ = (c_ & 7) ^ (r_ & 7);                                     \
      gl16(gb_ + (size_t)r_ * 1024 + sl_ * 16, sb_ + (wv * 64) * 16); }        \
    { const int c_ = tid + 512; const int r_ = c_ >> 3;                        \
      const int sl_ = (c_ & 7) ^ (r_ & 7);                                     \
      gl16(gb_ + (size_t)r_ * 1024 + sl_ * 16, sb_ + (512 + wv * 64) * 16); }  \
  }while(0)

  // prologue: tiles 0..2 in flight (after the 8 Qt loads; phase-0's
  // vmcnt(6) wait covers the older Qt loads automatically)
  STAGE(0); STAGE(1); STAGE(2);

  f32x4 acc[8];
#pragma unroll
  for (int i = 0; i < 8; ++i) acc[i] = (f32x4){0.f, 0.f, 0.f, 0.f};

  const int xrow = wv * 16 + lm;
  const int xsw  = (xrow & 7) << 4;

#define CONSUME(u) do{                                                         \
    const char* sb_ = ring + ((u) % RING) * XTILE;                             \
    const f32x4 xa_ = *(const f32x4*)(sb_ + xrow * 128 + ((lg * 32)      ^ xsw));\
    const f32x4 xb_ = *(const f32x4*)(sb_ + xrow * 128 + ((lg * 32 + 16) ^ xsw));\
    short8 a_;                                                                 \
    a_[0] = (short)f2bf(xa_[0]); a_[1] = (short)f2bf(xa_[1]);                  \
    a_[2] = (short)f2bf(xa_[2]); a_[3] = (short)f2bf(xa_[3]);                  \
    a_[4] = (short)f2bf(xb_[0]); a_[5] = (short)f2bf(xb_[1]);                  \
    a_[6] = (short)f2bf(xb_[2]); a_[7] = (short)f2bf(xb_[3]);                  \
    const int kb_ = ((u) & 7) * 64 + (lg << 4);                                \
    _Pragma("unroll")                                                          \
    for (int nt_ = 0; nt_ < 8; ++nt_){                                         \
      const int nl_ = nt_ * 16 + lm;                                           \
      const short8 b_ = *(const short8*)(qb + (nl_ << 9) +                     \
                                         (kb_ ^ ((nl_ & 15) << 5)));           \
      acc[nt_] = __builtin_amdgcn_mfma_f32_16x16x32_bf16(a_, b_, acc[nt_],     \
                                                         0, 0, 0);             \
    }                                                                          \
  }while(0)

#define STORECHUNK(c) do{                                                      \
    const size_t orow_ = rowbase + (size_t)(c) * TROWS + wv * 16 + lg * 4;     \
    _Pragma("unroll")                                                          \
    for (int nt_ = 0; nt_ < 8; ++nt_){                                         \
      _Pragma("unroll")                                                        \
      for (int r_ = 0; r_ < 4; ++r_){                                          \
        __builtin_nontemporal_store(acc[nt_][r_],                              \
            &Y[(orow_ + r_) * DDIM + half * 128 + nt_ * 16 + lm]);             \
      }                                                                        \
      acc[nt_] = (f32x4){0.f, 0.f, 0.f, 0.f};                                  \
    }                                                                          \
  }while(0)

#define PHASE(t) do{                                                           \
    if ((t) + AHEAD < NTILE) STAGE((t) + AHEAD);                               \
    asm volatile("s_waitcnt vmcnt(%0)" :: "n"(wcnt(t)) : "memory");            \
    __builtin_amdgcn_s_barrier();                                              \
    __builtin_amdgcn_sched_barrier(0);                                         \
    CONSUME(t);                                                                \
    if (((t) & 7) == 7) STORECHUNK((t) >> 3);                                  \
  }while(0)

  PHASE(0);  PHASE(1);  PHASE(2);  PHASE(3);
  PHASE(4);  PHASE(5);  PHASE(6);  PHASE(7);
  PHASE(8);  PHASE(9);  PHASE(10); PHASE(11);
  PHASE(12); PHASE(13); PHASE(14); PHASE(15);
  PHASE(16); PHASE(17); PHASE(18); PHASE(19);
  PHASE(20); PHASE(21); PHASE(22); PHASE(23);
  PHASE(24); PHASE(25); PHASE(26); PHASE(27);
  PHASE(28); PHASE(29); PHASE(30); PHASE(31);

#undef PHASE
#undef STORECHUNK
#undef CONSUME
#undef STAGE
}

extern "C" void kernel_launch(void* const* d_in, const int* in_sizes, int n_in,
                              void* d_out, int out_size, void* d_ws, size_t ws_size,
                              hipStream_t stream) {
  const float* X = (const float*)d_in[0];     // [131072, 256]
  const float* U = (const float*)d_in[1];     // [256, 256]
  float* Y = (float*)d_out;                   // [131072, 256]
  unsigned short* Qt = (unsigned short*)d_ws; // 256*256 bf16 = 128 KB scratch

  compute_q<<<32, 256, 0, stream>>>(U, Qt);
  gemm_xq<<<GBLK, 512, 0, stream>>>(X, Qt, Y);
}